// Round 1
// 754.486 us; speedup vs baseline: 1.0139x; 1.0139x over previous
//
#include <hip/hip_runtime.h>

// Problem constants
#define BB 64      // batch
#define SS 1024    // symbols (= values = d_model = 1024, all dims equal)
#define NN 1024    // generic K/N dim
#define PARTS 16   // K-split chunks for the big batched vec-mat passes
#define KC 64      // SS / PARTS

typedef float f4 __attribute__((ext_vector_type(4)));

// ---------------------------------------------------------------------------
// Big batched vec-mat pass, K-split into PARTS deterministic partials
// (NO atomics, NO zero-init dependency).
//   Cp[part, b, t] = sum_{k in chunk} a[b,k] * W[b*S*S + k*NN + t]
// ASRC selects where a[b,k] comes from:
//   0: gather  a[b,k] = qmask[b] * SM[b, qidx[b], k]   (walk1 on the fly)
//   1: reduce  a[b,k] = sum_p P[p, b, k]               (walk2 from pA partials)
//   2: direct  a[b,k] = A[b, k]                        (Wsum)
// REV: reverse batch order (L3 tail-residency heuristic for the 2nd SM pass).
// NT:  nontemporal W loads (single-use cold stream, don't pollute caches).
template<int ASRC, int REV, int NT>
__global__ __launch_bounds__(256) void k_walkp(const float* __restrict__ A,
                                               const float* __restrict__ P,
                                               const float* __restrict__ W,
                                               float* __restrict__ Cp,
                                               const int* __restrict__ qidx,
                                               const float* __restrict__ qmask) {
    const int part = blockIdx.x;
    const int b    = REV ? (gridDim.y - 1 - blockIdx.y) : blockIdx.y;
    const int k0   = part * KC;

    __shared__ float As[KC];
    if (threadIdx.x < KC) {
        float v;
        if (ASRC == 0) {
            int q = qidx[b];
            v = qmask[b] * W[(size_t)b * SS * SS + (size_t)q * SS + k0 + threadIdx.x];
        } else if (ASRC == 1) {
            v = 0.f;
            #pragma unroll
            for (int p = 0; p < PARTS; ++p)
                v += P[(size_t)p * BB * SS + b * SS + k0 + threadIdx.x];
        } else {
            v = A[b * SS + k0 + threadIdx.x];
        }
        As[threadIdx.x] = v;
    }
    __syncthreads();

    const float* Wp = W + (size_t)b * SS * SS + (size_t)k0 * NN + threadIdx.x * 4;
    f4 acc = {0.f, 0.f, 0.f, 0.f};
    for (int k = 0; k < KC; ++k) {
        f4 wv;
        if (NT) wv = __builtin_nontemporal_load((const f4*)(Wp + (size_t)k * NN));
        else    wv = *(const f4*)(Wp + (size_t)k * NN);
        float a = As[k];
        acc.x = fmaf(a, wv.x, acc.x);
        acc.y = fmaf(a, wv.y, acc.y);
        acc.z = fmaf(a, wv.z, acc.z);
        acc.w = fmaf(a, wv.w, acc.w);
    }
    // deterministic partial store (float4, fully coalesced, no RMW)
    f4* c = (f4*)(Cp + (size_t)part * BB * SS + (size_t)b * SS) + threadIdx.x;
    *c = acc;
}

// ---------------------------------------------------------------------------
// Wsum[b,s] = m*SM[b,q,s] (walk1) + sum_p pA[p,b,s] (walk2)
//           + sum_p pB[p,b,s] (walk3) + m*(s==q) (walk0 one-hot)
// P points at pA; pB is contiguous after it, so we reduce 2*PARTS slabs.
__global__ void k_wsum(const float* __restrict__ SM,
                       const float* __restrict__ P,
                       const int* __restrict__ qidx, const float* __restrict__ qmask,
                       float* __restrict__ Wsum) {
    int b = blockIdx.x;
    int q = qidx[b];
    float m = qmask[b];
    int s0 = threadIdx.x * 4;

    f4 acc = m * (*(const f4*)(SM + (size_t)b * SS * SS + (size_t)q * SS + s0));
    #pragma unroll
    for (int p = 0; p < 2 * PARTS; ++p)
        acc += *(const f4*)(P + (size_t)p * BB * SS + b * SS + s0);
    int d = q - s0;
    if (d >= 0 && d < 4) acc[d] += m;
    *(f4*)(Wsum + b * SS + s0) = acc;
}

// ---------------------------------------------------------------------------
// Small skinny GEMM (shared weights), dual-problem via blockIdx.z.
// C[r,t] += sum_k A[r,k] * W[k*NN + t];  ROWS rows/block, K-split + atomics.
// ARz: A for that z-half is reconstructed by reducing PARTS partial slabs in P
//      (used for accv = sum_p pC without ever materializing accv).
template<int ROWS, int KCS, int AR0, int AR1>
__global__ __launch_bounds__(256) void k_small(const float* __restrict__ A0,
                                               const float* __restrict__ W0,
                                               float* __restrict__ C0,
                                               const float* __restrict__ A1,
                                               const float* __restrict__ W1,
                                               float* __restrict__ C1,
                                               const float* __restrict__ P) {
    const int   ar = blockIdx.z ? AR1 : AR0;
    const float* A = blockIdx.z ? A1 : A0;
    const float* W = blockIdx.z ? W1 : W0;
    float*       C = blockIdx.z ? C1 : C0;
    const int k0 = blockIdx.x * KCS;
    const int r0 = blockIdx.y * ROWS;

    __shared__ float As[ROWS * KCS];
    for (int i = threadIdx.x; i < ROWS * KCS; i += 256) {
        int r = i / KCS, k = i % KCS;
        float v;
        if (ar) {
            v = 0.f;
            #pragma unroll
            for (int p = 0; p < PARTS; ++p)
                v += P[(size_t)p * BB * SS + (size_t)(r0 + r) * SS + k0 + k];
        } else {
            v = A[(r0 + r) * NN + k0 + k];
        }
        As[i] = v;
    }
    __syncthreads();

    const float* Wp = W + (size_t)k0 * NN + threadIdx.x * 4;
    float acc[ROWS][4];
    #pragma unroll
    for (int r = 0; r < ROWS; ++r) {
        acc[r][0] = 0.f; acc[r][1] = 0.f; acc[r][2] = 0.f; acc[r][3] = 0.f;
    }
    for (int k = 0; k < KCS; ++k) {
        float4 wv = *(const float4*)(Wp + (size_t)k * NN);
        #pragma unroll
        for (int r = 0; r < ROWS; ++r) {
            float a = As[r * KCS + k];
            acc[r][0] = fmaf(a, wv.x, acc[r][0]);
            acc[r][1] = fmaf(a, wv.y, acc[r][1]);
            acc[r][2] = fmaf(a, wv.z, acc[r][2]);
            acc[r][3] = fmaf(a, wv.w, acc[r][3]);
        }
    }
    const int t = threadIdx.x * 4;
    #pragma unroll
    for (int r = 0; r < ROWS; ++r) {
        float* c = C + (size_t)(r0 + r) * NN + t;
        unsafeAtomicAdd(c + 0, acc[r][0]);
        unsafeAtomicAdd(c + 1, acc[r][1]);
        unsafeAtomicAdd(c + 2, acc[r][2]);
        unsafeAtomicAdd(c + 3, acc[r][3]);
    }
}

// In-place bias + tanh-approx GELU on h0 (y=0) / h1 (y=1)
__global__ void k_biasgelu(float* __restrict__ h0, float* __restrict__ h1,
                           const float* __restrict__ b0, const float* __restrict__ b1) {
    float* h = blockIdx.y ? h1 : h0;
    const float* bias = blockIdx.y ? b1 : b0;
    int b = blockIdx.x;
    int t = threadIdx.x * 4;
    #pragma unroll
    for (int j = 0; j < 4; ++j) {
        int d = t + j;
        float x = h[b * NN + d] + bias[d];
        float c = 0.7978845608028654f * (x + 0.044715f * x * x * x);
        h[b * NN + d] = 0.5f * x * (1.0f + tanhf(c));
    }
}

// d_out = src + bias; y=0: logits (offset 0), y=1: feedback (offset B*N)
__global__ void k_out(const float* __restrict__ lg, const float* __restrict__ fb,
                      const float* __restrict__ bo2, const float* __restrict__ bf2,
                      float* __restrict__ out) {
    int half = blockIdx.y;
    const float* src = half ? fb : lg;
    const float* bias = half ? bf2 : bo2;
    float* dst = out + (size_t)half * BB * NN;
    int b = blockIdx.x;
    int t = threadIdx.x * 4;
    #pragma unroll
    for (int j = 0; j < 4; ++j) {
        int n = t + j;
        dst[b * NN + n] = src[b * NN + n] + bias[n];
    }
}

extern "C" void kernel_launch(void* const* d_in, const int* in_sizes, int n_in,
                              void* d_out, int out_size, void* d_ws, size_t ws_size,
                              hipStream_t stream) {
    const float* MM   = (const float*)d_in[0];   // map_memory  [B,S,V]
    const float* SM   = (const float*)d_in[1];   // step_memory [B,S,S]
    const int*   qidx = (const int*)d_in[2];     // query_idx   [B]
    const float* qmask= (const float*)d_in[3];   // query_mask  [B]
    const float* sb   = (const float*)d_in[4];   // symbol_bank [S,D]
    const float* vb   = (const float*)d_in[5];   // value_bank  [V,D]
    const float* Wo1  = (const float*)d_in[6];
    const float* bo1  = (const float*)d_in[7];
    const float* Wo2  = (const float*)d_in[8];
    const float* bo2  = (const float*)d_in[9];
    const float* Wf1  = (const float*)d_in[10];
    const float* bf1  = (const float*)d_in[11];
    const float* Wf2  = (const float*)d_in[12];
    const float* bf2  = (const float*)d_in[13];
    float* out = (float*)d_out;

    float* ws = (float*)d_ws;
    // Workspace layout (floats). Partial slabs are written fully each pass —
    // no zero-init needed for them.
    float* pA   = ws;                         // [16][64][1024] walk2 partials
    float* pB   = ws + 1048576;               // [16][64][1024] walk3 partials
    float* pC   = ws + 2097152;               // [16][64][1024] accv  partials
    float* Wsum = ws + 3145728;               // [64][1024]
    float* gs   = ws + 3211264;               // [64][1024]  atomic-accumulated
    float* h_o  = ws + 3276800;               // [64][1024]  atomic-accumulated
    float* h_f  = ws + 3342336;               // [64][1024]  atomic-accumulated
    float* lg   = ws + 3407872;               // [64][1024]  atomic-accumulated
    float* fb   = ws + 3473408;               // [64][1024]  atomic-accumulated

    // Only the small-GEMM accumulators need zeroing (1.25 MB, ~0.2 µs);
    // none of the big streaming passes depend on this memset.
    hipMemsetAsync(gs, 0, 5 * 65536 * sizeof(float), stream);

    // pass 1: walk2 partials = (m * SM[b,q,:]) @ SM[b]   (gather fused)
    k_walkp<0, 0, 0><<<dim3(PARTS, BB), 256, 0, stream>>>(nullptr, nullptr, SM, pA, qidx, qmask);
    // pass 2: walk3 partials = (sum_p pA) @ SM[b]        (reverse order: L3 re-hit)
    k_walkp<1, 1, 0><<<dim3(PARTS, BB), 256, 0, stream>>>(nullptr, pA, SM, pB, qidx, qmask);
    // Wsum = walk1 + walk2 + walk3 + one-hot  (reduces pA and pB in one go)
    k_wsum<<<BB, 256, 0, stream>>>(SM, pA, qidx, qmask, Wsum);
    // pass 3: accv partials = Wsum @ MM[b]    (cold single-use stream: NT loads)
    k_walkp<2, 0, 1><<<dim3(PARTS, BB), 256, 0, stream>>>(Wsum, nullptr, MM, pC, qidx, qmask);
    // graph_state = Wsum @ symbol_bank + (sum_p pC) @ value_bank
    k_small<8, 128, 0, 1><<<dim3(8, 8, 2), 256, 0, stream>>>(Wsum, sb, gs, nullptr, vb, gs, pC);
    // h_o = gs @ Wo1 ; h_f = gs @ Wf1
    k_small<8, 128, 0, 0><<<dim3(8, 8, 2), 256, 0, stream>>>(gs, Wo1, h_o, gs, Wf1, h_f, nullptr);
    k_biasgelu<<<dim3(BB, 2), 256, 0, stream>>>(h_o, h_f, bo1, bf1);
    // lg = gelu_h_o @ Wo2 ; fb = gelu_h_f @ Wf2
    k_small<8, 128, 0, 0><<<dim3(8, 8, 2), 256, 0, stream>>>(h_o, Wo2, lg, h_f, Wf2, fb, nullptr);
    k_out<<<dim3(BB, 2), 256, 0, stream>>>(lg, fb, bo2, bf2, out);
}

// Round 2
// 734.454 us; speedup vs baseline: 1.0416x; 1.0273x over previous
//
#include <hip/hip_runtime.h>

// Problem constants
#define BB 64      // batch
#define SS 1024    // symbols (= values = d_model = 1024, all dims equal)
#define NN 1024    // generic K/N dim
#define PARTS 32   // K-split chunks for the big batched vec-mat passes
#define KC 32      // SS / PARTS

typedef float f4 __attribute__((ext_vector_type(4)));

// ---------------------------------------------------------------------------
// Big batched vec-mat pass, K-split into PARTS deterministic partials
// (NO atomics, NO zero-init dependency).
//   Cp[part, b, t] = sum_{k in chunk} a[b,k] * W[b*S*S + k*NN + t]
// ASRC: 0 gather (walk1 on the fly), 1 reduce partial slabs, 2 direct A.
// REV:  reverse batch order (L3 tail-residency for the 2nd SM pass).
// NT:   nontemporal W loads (single-use cold stream).
template<int ASRC, int REV, int NT>
__global__ __launch_bounds__(256) void k_walkp(const float* __restrict__ A,
                                               const float* __restrict__ P,
                                               const float* __restrict__ W,
                                               float* __restrict__ Cp,
                                               const int* __restrict__ qidx,
                                               const float* __restrict__ qmask) {
    const int part = blockIdx.x;
    const int b    = REV ? (gridDim.y - 1 - blockIdx.y) : blockIdx.y;
    const int k0   = part * KC;

    __shared__ float As[KC];
    if (threadIdx.x < KC) {
        float v;
        if (ASRC == 0) {
            int q = qidx[b];
            v = qmask[b] * W[(size_t)b * SS * SS + (size_t)q * SS + k0 + threadIdx.x];
        } else if (ASRC == 1) {
            v = 0.f;
            #pragma unroll
            for (int p = 0; p < PARTS; ++p)
                v += P[(size_t)p * BB * SS + b * SS + k0 + threadIdx.x];
        } else {
            v = A[b * SS + k0 + threadIdx.x];
        }
        As[threadIdx.x] = v;
    }
    __syncthreads();

    const float* Wp = W + (size_t)b * SS * SS + (size_t)k0 * NN + threadIdx.x * 4;
    f4 acc = {0.f, 0.f, 0.f, 0.f};
    #pragma unroll 8
    for (int k = 0; k < KC; ++k) {
        f4 wv;
        if (NT) wv = __builtin_nontemporal_load((const f4*)(Wp + (size_t)k * NN));
        else    wv = *(const f4*)(Wp + (size_t)k * NN);
        float a = As[k];
        acc.x = fmaf(a, wv.x, acc.x);
        acc.y = fmaf(a, wv.y, acc.y);
        acc.z = fmaf(a, wv.z, acc.z);
        acc.w = fmaf(a, wv.w, acc.w);
    }
    f4* c = (f4*)(Cp + (size_t)part * BB * SS + (size_t)b * SS) + threadIdx.x;
    *c = acc;
}

// ---------------------------------------------------------------------------
// Wsum[b,s] = m*SM[b,q,s] (walk1) + sum_p pA[p,b,s] (walk2)
//           + sum_p pB[p,b,s] (walk3) + m*(s==q) (one-hot)
// pB is contiguous after pA: reduce 2*PARTS slabs in one loop.
__global__ void k_wsum(const float* __restrict__ SM,
                       const float* __restrict__ P,
                       const int* __restrict__ qidx, const float* __restrict__ qmask,
                       float* __restrict__ Wsum) {
    int b = blockIdx.x;
    int q = qidx[b];
    float m = qmask[b];
    int s0 = threadIdx.x * 4;

    f4 acc = m * (*(const f4*)(SM + (size_t)b * SS * SS + (size_t)q * SS + s0));
    #pragma unroll
    for (int p = 0; p < 2 * PARTS; ++p)
        acc += *(const f4*)(P + (size_t)p * BB * SS + b * SS + s0);
    int d = q - s0;
    if (d >= 0 && d < 4) acc[d] += m;
    *(f4*)(Wsum + b * SS + s0) = acc;
}

// ---------------------------------------------------------------------------
// Small skinny GEMM (shared weights), dual-problem via blockIdx.z.
// C[r,t] += sum_k A[r,k] * W[k*NN + t];  ROWS rows/block, K-split + atomics.
// ARz:  reconstruct A for that z-half by reducing PARTS partial slabs in P.
// GELU: apply x -> gelu(x + bias[k]) to A elements at staging time (fuses the
//       bias+activation of the previous layer into this GEMM's A-load).
template<int ROWS, int KCS, int AR0, int AR1, int GELU>
__global__ __launch_bounds__(256) void k_small(const float* __restrict__ A0,
                                               const float* __restrict__ W0,
                                               float* __restrict__ C0,
                                               const float* __restrict__ A1,
                                               const float* __restrict__ W1,
                                               float* __restrict__ C1,
                                               const float* __restrict__ P,
                                               const float* __restrict__ bias0,
                                               const float* __restrict__ bias1) {
    const int   ar  = blockIdx.z ? AR1 : AR0;
    const float* A  = blockIdx.z ? A1 : A0;
    const float* W  = blockIdx.z ? W1 : W0;
    float*       C  = blockIdx.z ? C1 : C0;
    const float* bi = blockIdx.z ? bias1 : bias0;
    const int k0 = blockIdx.x * KCS;
    const int r0 = blockIdx.y * ROWS;

    __shared__ float As[ROWS * KCS];
    for (int i = threadIdx.x; i < ROWS * KCS; i += 256) {
        int r = i / KCS, k = i % KCS;
        float v;
        if (ar) {
            v = 0.f;
            #pragma unroll
            for (int p = 0; p < PARTS; ++p)
                v += P[(size_t)p * BB * SS + (size_t)(r0 + r) * SS + k0 + k];
        } else {
            v = A[(r0 + r) * NN + k0 + k];
        }
        if (GELU) {
            float x = v + bi[k0 + k];
            float c = 0.7978845608028654f * (x + 0.044715f * x * x * x);
            v = 0.5f * x * (1.0f + tanhf(c));
        }
        As[i] = v;
    }
    __syncthreads();

    const float* Wp = W + (size_t)k0 * NN + threadIdx.x * 4;
    float acc[ROWS][4];
    #pragma unroll
    for (int r = 0; r < ROWS; ++r) {
        acc[r][0] = 0.f; acc[r][1] = 0.f; acc[r][2] = 0.f; acc[r][3] = 0.f;
    }
    #pragma unroll 8
    for (int k = 0; k < KCS; ++k) {
        float4 wv = *(const float4*)(Wp + (size_t)k * NN);
        #pragma unroll
        for (int r = 0; r < ROWS; ++r) {
            float a = As[r * KCS + k];
            acc[r][0] = fmaf(a, wv.x, acc[r][0]);
            acc[r][1] = fmaf(a, wv.y, acc[r][1]);
            acc[r][2] = fmaf(a, wv.z, acc[r][2]);
            acc[r][3] = fmaf(a, wv.w, acc[r][3]);
        }
    }
    const int t = threadIdx.x * 4;
    #pragma unroll
    for (int r = 0; r < ROWS; ++r) {
        float* c = C + (size_t)(r0 + r) * NN + t;
        unsafeAtomicAdd(c + 0, acc[r][0]);
        unsafeAtomicAdd(c + 1, acc[r][1]);
        unsafeAtomicAdd(c + 2, acc[r][2]);
        unsafeAtomicAdd(c + 3, acc[r][3]);
    }
}

// ---------------------------------------------------------------------------
// Init: zero the three atomic accumulators; pre-load d_out with the final
// biases so the last GEMM accumulates straight into d_out (replaces k_out).
__global__ void k_init(float* __restrict__ gs, float* __restrict__ h_o,
                       float* __restrict__ h_f, float* __restrict__ out,
                       const float* __restrict__ bo2, const float* __restrict__ bf2) {
    int b = blockIdx.x;
    int t = threadIdx.x * 4;
    f4 z = {0.f, 0.f, 0.f, 0.f};
    switch (blockIdx.y) {
        case 0: *(f4*)(gs  + b * NN + t) = z; break;
        case 1: *(f4*)(h_o + b * NN + t) = z; break;
        case 2: *(f4*)(h_f + b * NN + t) = z; break;
        case 3: *(f4*)(out + (size_t)b * NN + t) = *(const f4*)(bo2 + t); break;
        case 4: *(f4*)(out + (size_t)(BB + b) * NN + t) = *(const f4*)(bf2 + t); break;
    }
}

extern "C" void kernel_launch(void* const* d_in, const int* in_sizes, int n_in,
                              void* d_out, int out_size, void* d_ws, size_t ws_size,
                              hipStream_t stream) {
    const float* MM   = (const float*)d_in[0];   // map_memory  [B,S,V]
    const float* SM   = (const float*)d_in[1];   // step_memory [B,S,S]
    const int*   qidx = (const int*)d_in[2];     // query_idx   [B]
    const float* qmask= (const float*)d_in[3];   // query_mask  [B]
    const float* sb   = (const float*)d_in[4];   // symbol_bank [S,D]
    const float* vb   = (const float*)d_in[5];   // value_bank  [V,D]
    const float* Wo1  = (const float*)d_in[6];
    const float* bo1  = (const float*)d_in[7];
    const float* Wo2  = (const float*)d_in[8];
    const float* bo2  = (const float*)d_in[9];
    const float* Wf1  = (const float*)d_in[10];
    const float* bf1  = (const float*)d_in[11];
    const float* Wf2  = (const float*)d_in[12];
    const float* bf2  = (const float*)d_in[13];
    float* out = (float*)d_out;

    float* ws = (float*)d_ws;
    // Workspace layout (floats). Partial slabs are fully written each pass.
    float* pA   = ws;                         // [32][64][1024] walk2 partials
    float* pB   = ws + 2097152;               // [32][64][1024] walk3 partials
    float* pC   = ws + 4194304;               // [32][64][1024] accv  partials
    float* Wsum = ws + 6291456;               // [64][1024]
    float* gs   = ws + 6356992;               // [64][1024]  atomic-accumulated
    float* h_o  = ws + 6422528;               // [64][1024]  atomic-accumulated
    float* h_f  = ws + 6488064;               // [64][1024]  atomic-accumulated

    // zero accumulators + bias-preload d_out (replaces memset + k_out)
    k_init<<<dim3(BB, 5), 256, 0, stream>>>(gs, h_o, h_f, out, bo2, bf2);

    // pass 1: walk2 partials = (m * SM[b,q,:]) @ SM[b]   (gather fused)
    k_walkp<0, 0, 0><<<dim3(PARTS, BB), 256, 0, stream>>>(nullptr, nullptr, SM, pA, qidx, qmask);
    // pass 2: walk3 partials = (sum_p pA) @ SM[b]        (reverse order: L3 re-hit)
    k_walkp<1, 1, 0><<<dim3(PARTS, BB), 256, 0, stream>>>(nullptr, pA, SM, pB, qidx, qmask);
    // Wsum = walk1 + walk2 + walk3 + one-hot
    k_wsum<<<BB, 256, 0, stream>>>(SM, pA, qidx, qmask, Wsum);
    // pass 3: accv partials = Wsum @ MM[b]    (cold single-use stream: NT loads)
    k_walkp<2, 0, 1><<<dim3(PARTS, BB), 256, 0, stream>>>(Wsum, nullptr, MM, pC, qidx, qmask);
    // graph_state = Wsum @ symbol_bank + (sum_p pC) @ value_bank
    k_small<8, 64, 0, 1, 0><<<dim3(16, 8, 2), 256, 0, stream>>>(
        Wsum, sb, gs, nullptr, vb, gs, pC, nullptr, nullptr);
    // h_o = gs @ Wo1 ; h_f = gs @ Wf1
    k_small<8, 64, 0, 0, 0><<<dim3(16, 8, 2), 256, 0, stream>>>(
        gs, Wo1, h_o, gs, Wf1, h_f, nullptr, nullptr, nullptr);
    // out_lg = gelu(h_o + bo1) @ Wo2 + bo2 ; out_fb = gelu(h_f + bf1) @ Wf2 + bf2
    // (gelu+bias fused into A-staging; bo2/bf2 pre-loaded into d_out by k_init)
    k_small<8, 64, 0, 0, 1><<<dim3(16, 8, 2), 256, 0, stream>>>(
        h_o, Wo2, out, h_f, Wf2, out + (size_t)BB * NN, nullptr, bo1, bf1);
}